// Round 2
// baseline (199.976 us; speedup 1.0000x reference)
//
#include <hip/hip_runtime.h>

#define N_Q 50000
#define H_NB 32
#define K_KP 15
#define C_CH 128
#define KP_EXT 1.2f

__global__ __launch_bounds__(128, 8)
void kpconv_dw_kernel(const float* __restrict__ q_pts,
                      const float* __restrict__ s_pts,
                      const int*   __restrict__ inds,
                      const float* __restrict__ x,
                      const float* __restrict__ kp,
                      const float* __restrict__ dw,
                      const float* __restrict__ bias,
                      float*       __restrict__ out)
{
    __shared__ int   s_idx[H_NB];
    __shared__ float s_pos[H_NB][3];
    __shared__ float s_kp[K_KP * 3];
    __shared__ float s_w[H_NB][K_KP];

    const int n = blockIdx.x;
    const int t = threadIdx.x;

    // stage kernel points (45 floats)
    if (t < K_KP * 3) s_kp[t] = kp[t];

    // stage neighbor indices + relative positions
    if (t < H_NB) {
        const float qx = q_pts[n * 3 + 0];
        const float qy = q_pts[n * 3 + 1];
        const float qz = q_pts[n * 3 + 2];
        int idx = inds[n * H_NB + t];
        s_idx[t] = idx;
        s_pos[t][0] = s_pts[idx * 3 + 0] - qx;
        s_pos[t][1] = s_pts[idx * 3 + 1] - qy;
        s_pos[t][2] = s_pts[idx * 3 + 2] - qz;
    }
    __syncthreads();

    // 480 (h,k) weight computations over 128 threads
    for (int p = t; p < H_NB * K_KP; p += 128) {
        const int h = p / K_KP;
        const int k = p - h * K_KP;
        const float dx = s_pos[h][0] - s_kp[k * 3 + 0];
        const float dy = s_pos[h][1] - s_kp[k * 3 + 1];
        const float dz = s_pos[h][2] - s_kp[k * 3 + 2];
        const float d = sqrtf(fmaf(dx, dx, fmaf(dy, dy, dz * dz)));
        const float w = 1.0f - d * (1.0f / KP_EXT);
        s_w[h][k] = w > 0.0f ? w : 0.0f;
    }
    __syncthreads();

    // channel phase: one thread per channel
    const int c = t;
    float dwr[K_KP];
#pragma unroll
    for (int k = 0; k < K_KP; ++k) dwr[k] = dw[k * C_CH + c];

    float acc = bias[c];
#pragma unroll 4
    for (int h = 0; h < H_NB; ++h) {
        float cw = 0.0f;
#pragma unroll
        for (int k = 0; k < K_KP; ++k) cw = fmaf(s_w[h][k], dwr[k], cw);
        acc = fmaf(cw, x[(long)s_idx[h] * C_CH + c], acc);
    }
    out[n * C_CH + c] = acc;
}

extern "C" void kernel_launch(void* const* d_in, const int* in_sizes, int n_in,
                              void* d_out, int out_size, void* d_ws, size_t ws_size,
                              hipStream_t stream) {
    const float* q_pts = (const float*)d_in[0];
    const float* s_pts = (const float*)d_in[1];
    const int*   inds  = (const int*)  d_in[2];
    const float* x     = (const float*)d_in[3];
    const float* kp    = (const float*)d_in[4];
    const float* dw    = (const float*)d_in[5];
    const float* bias  = (const float*)d_in[6];
    float* out = (float*)d_out;

    kpconv_dw_kernel<<<N_Q, 128, 0, stream>>>(q_pts, s_pts, inds, x, kp, dw, bias, out);
}